// Round 1
// baseline (384.819 us; speedup 1.0000x reference)
//
#include <hip/hip_runtime.h>

// ---------------------------------------------------------------------------
// Fused attention: qp = q@Wq+bq ; kp = k@Wk+bk ; vp = v@Wv+bv
// S = qp kp^T / 16 ; A = softmax(S) ; A = where(threefry_mask, A/0.8, 0)
// out = A vp.   B=4, L=4096, D=256, DV=64.  fp32 in/out, bf16 MFMA internally.
// ---------------------------------------------------------------------------

typedef short s16x8 __attribute__((ext_vector_type(8)));   // 8 bf16 (4 VGPR)
typedef float f32x4 __attribute__((ext_vector_type(4)));

#define L    4096
#define DM   256
#define DV   64
#define MTOT 16384            // B*L rows

__device__ __forceinline__ short f2bf(float f) {           // RNE fp32->bf16
  unsigned u = __builtin_bit_cast(unsigned, f);
  u += 0x7FFFu + ((u >> 16) & 1u);
  return (short)(u >> 16);
}

__device__ __forceinline__ unsigned rotl32c(unsigned x, int r) {
  return (x << r) | (x >> (32 - r));                       // -> v_alignbit_b32
}

// JAX partitionable threefry2x32, key=(0,42), counter=(0,ctr).
// keep = uniform(bits1^bits2) < 0.8f  <=>  bits < 6710887*512
__device__ __forceinline__ unsigned tf_keep(unsigned ctr) {
  unsigned x0 = 0u;
  unsigned x1 = ctr + 42u;                                 // + ks[1]
#define TFR(r) { x0 += x1; x1 = rotl32c(x1, r); x1 ^= x0; }
  TFR(13) TFR(15) TFR(26) TFR(6)
  x0 += 42u;          x1 += 0x1BD11BF1u;                   // ks2=0x1BD11BDA^42, +1
  TFR(17) TFR(29) TFR(16) TFR(24)
  x0 += 0x1BD11BF0u;  x1 += 2u;
  TFR(13) TFR(15) TFR(26) TFR(6)
  /* x0 += 0 */       x1 += 45u;                           // 42 + 3
  TFR(17) TFR(29) TFR(16) TFR(24)
  x0 += 42u;          x1 += 0x1BD11BF4u;                   // ks2 + 4
  TFR(13) TFR(15) TFR(26) TFR(6)
  x0 += 0x1BD11BF0u;  x1 += 5u;
#undef TFR
  return ((x0 ^ x1) < 3435974144u) ? 1u : 0u;
}

// ---------------------------------------------------------------------------
// Projection: out[M,N](bf16) = A[M,K](f32) @ W[K,N](f32) + bias.
// Wave = 16 rows; block = 64 rows. TRANS_OUT stores out^T per-batch for V:
// vpT[(b*64+n)*4096 + key].
// MFMA 16x16x32 bf16 frags: A/B: lane (l&15)=m/n, k=(l>>4)*8+j ;
// C: row=(l>>4)*4+j, col=l&15  (m89/m91-verified layout).
// ---------------------------------------------------------------------------
template <int K, int N, bool TRANS_OUT>
__global__ __launch_bounds__(256) void proj_kernel(
    const float* __restrict__ A, const float* __restrict__ W,
    const float* __restrict__ bias, short* __restrict__ out) {
  const int lane = threadIdx.x & 63;
  const int wv   = threadIdx.x >> 6;
  const int l15 = lane & 15, l4 = lane >> 4;
  const int rowbase = blockIdx.x * 64 + wv * 16;
  constexpr int NT = N / 16;
  constexpr int KC = K / 32;
  f32x4 acc[NT];
#pragma unroll
  for (int i = 0; i < NT; ++i) acc[i] = (f32x4){0.f, 0.f, 0.f, 0.f};
  const int arow = rowbase + l15;
  for (int kc = 0; kc < KC; ++kc) {
    const f32x4* ap = (const f32x4*)(A + (size_t)arow * K + kc * 32 + l4 * 8);
    f32x4 a0 = ap[0], a1 = ap[1];
    s16x8 af;
#pragma unroll
    for (int j = 0; j < 4; ++j) { af[j] = f2bf(a0[j]); af[4 + j] = f2bf(a1[j]); }
#pragma unroll
    for (int nt = 0; nt < NT; ++nt) {
      const float* wp = W + (size_t)(kc * 32 + l4 * 8) * N + nt * 16 + l15;
      s16x8 bf;
#pragma unroll
      for (int j = 0; j < 8; ++j) bf[j] = f2bf(wp[(size_t)j * N]);
      acc[nt] = __builtin_amdgcn_mfma_f32_16x16x32_bf16(af, bf, acc[nt], 0, 0, 0);
    }
  }
#pragma unroll
  for (int nt = 0; nt < NT; ++nt) {
    const int gcol = nt * 16 + l15;
    const float bv = bias[gcol];
#pragma unroll
    for (int j = 0; j < 4; ++j) {
      const int grow = rowbase + l4 * 4 + j;
      const float vv = acc[nt][j] + bv;
      if (TRANS_OUT) {
        const int b = grow >> 12, key = grow & 4095;
        out[(size_t)(b * 64 + gcol) * L + key] = f2bf(vv);
      } else {
        out[(size_t)grow * N + gcol] = f2bf(vv);
      }
    }
  }
}

// ---------------------------------------------------------------------------
// Fused flash attention + exact-threefry dropout.
// Block: 256 thr (4 waves), 64 q-rows (16/wave). K-blocks of 64 keys.
// kbuf [64][256] bf16 (XOR-swizzled), vbuf = V^T [64dv][64k] (swizzled),
// pbuf per-wave [16][64] for the C-frag -> A-frag transpose of P.
// out = (sum keep*e*v) / (0.8 * sum e); e = exp2(score * log2e/16).
// ---------------------------------------------------------------------------
__global__ __launch_bounds__(256) void attn_kernel(
    const short* __restrict__ qp, const short* __restrict__ kp,
    const short* __restrict__ vpT, float* __restrict__ out) {
  __shared__ __align__(16) short kbuf[64 * 256];
  __shared__ __align__(16) short vbuf[64 * 64];
  __shared__ __align__(16) short pbuf[4][16 * 64];
  const int tid = threadIdx.x;
  const int lane = tid & 63, wv = tid >> 6;
  const int l15 = lane & 15, l4 = lane >> 4;
  const int qt = blockIdx.x, b = blockIdx.y;
  const int qrow0 = b * L + qt * 64 + wv * 16;  // global row in [MTOT] space

  // Q fragments held in registers for the whole kernel (8 k-chunks of 32)
  s16x8 qf[8];
#pragma unroll
  for (int kc = 0; kc < 8; ++kc)
    qf[kc] = *(const s16x8*)(qp + (size_t)(qrow0 + l15) * DM + kc * 32 + l4 * 8);

  f32x4 accO[4];
#pragma unroll
  for (int i = 0; i < 4; ++i) accO[i] = (f32x4){0.f, 0.f, 0.f, 0.f};
  float zpart[4] = {0.f, 0.f, 0.f, 0.f};

  const unsigned qglob = (unsigned)qrow0;  // == b*4096 + q_row_base
  constexpr float CEXP = 0.09016844005556021f;  // log2(e)/16

  for (int kb = 0; kb < 64; ++kb) {
    __syncthreads();  // previous iteration's LDS reads complete
    {  // stage K block: 64 rows x 512B, swizzle elem ^= (row&7)<<3
      const short* src = kp + (size_t)(b * L + kb * 64) * DM;
#pragma unroll
      for (int it = 0; it < 8; ++it) {
        const int c = it * 256 + tid;
        const int row = c >> 5, off = (c & 31) * 8;
        const int e = (row * 256 + off) ^ ((row & 7) << 3);
        *(s16x8*)(kbuf + e) = *(const s16x8*)(src + (size_t)row * DM + off);
      }
      // stage V^T block: 64 dv-rows x 128B
      const short* vsrc = vpT + (size_t)b * 64 * L + kb * 64;
#pragma unroll
      for (int it = 0; it < 2; ++it) {
        const int c = it * 256 + tid;
        const int row = c >> 3, off = (c & 7) * 8;
        const int e = (row * 64 + off) ^ ((row & 7) << 3);
        *(s16x8*)(vbuf + e) = *(const s16x8*)(vsrc + (size_t)row * L + off);
      }
    }
    __syncthreads();

    // ---- QK^T: 4 key-tiles x 8 k-chunks ----
    f32x4 sf[4];
#pragma unroll
    for (int kt = 0; kt < 4; ++kt) sf[kt] = (f32x4){0.f, 0.f, 0.f, 0.f};
#pragma unroll
    for (int kc = 0; kc < 8; ++kc) {
#pragma unroll
      for (int kt = 0; kt < 4; ++kt) {
        const int row = kt * 16 + l15;
        const int e = (row * 256 + kc * 32 + l4 * 8) ^ ((row & 7) << 3);
        const s16x8 kf = *(const s16x8*)(kbuf + e);
        sf[kt] = __builtin_amdgcn_mfma_f32_16x16x32_bf16(qf[kc], kf, sf[kt], 0, 0, 0);
      }
    }

    // ---- dropout masks: 16 independent threefry chains (ILP) ----
    unsigned keep = 0;
#pragma unroll
    for (int kt = 0; kt < 4; ++kt) {
#pragma unroll
      for (int j = 0; j < 4; ++j) {
        const unsigned q = qglob + (unsigned)(l4 * 4 + j);
        const unsigned idx = (q << 12) + (unsigned)(kb * 64 + kt * 16 + l15);
        keep |= tf_keep(idx) << (kt * 4 + j);
      }
    }

    // ---- exp, Z accumulation, store masked P (bf16) into pbuf ----
#pragma unroll
    for (int kt = 0; kt < 4; ++kt) {
#pragma unroll
      for (int j = 0; j < 4; ++j) {
        const float e = exp2f(sf[kt][j] * CEXP);
        zpart[j] += e;
        const float pd = ((keep >> (kt * 4 + j)) & 1u) ? e : 0.0f;
        const int row = l4 * 4 + j, col = kt * 16 + l15;
        const int pe = (row * 64 + col) ^ ((row & 7) << 3);
        pbuf[wv][pe] = f2bf(pd);
      }
    }
    __syncthreads();

    // ---- PV: P[16x64] @ V[64x64] ----
#pragma unroll
    for (int ks = 0; ks < 2; ++ks) {
      const int pe = (l15 * 64 + ks * 32 + l4 * 8) ^ ((l15 & 7) << 3);
      const s16x8 pa = *(const s16x8*)(&pbuf[wv][0] + pe);
#pragma unroll
      for (int nt = 0; nt < 4; ++nt) {
        const int vrow = nt * 16 + l15;
        const int ve = (vrow * 64 + ks * 32 + l4 * 8) ^ ((vrow & 7) << 3);
        const s16x8 vb = *(const s16x8*)(vbuf + ve);
        accO[nt] = __builtin_amdgcn_mfma_f32_16x16x32_bf16(pa, vb, accO[nt], 0, 0, 0);
      }
    }
  }

  // ---- epilogue: reduce Z across the 16-lane group, normalize, store ----
#pragma unroll
  for (int j = 0; j < 4; ++j) {
    float z = zpart[j];
    z += __shfl_xor(z, 1);
    z += __shfl_xor(z, 2);
    z += __shfl_xor(z, 4);
    z += __shfl_xor(z, 8);
    const float inv = 1.0f / (0.8f * z);
    const int grow = qrow0 + l4 * 4 + j;
#pragma unroll
    for (int nt = 0; nt < 4; ++nt)
      out[(size_t)grow * DV + nt * 16 + l15] = accO[nt][j] * inv;
  }
}

// ---------------------------------------------------------------------------
extern "C" void kernel_launch(void* const* d_in, const int* in_sizes, int n_in,
                              void* d_out, int out_size, void* d_ws, size_t ws_size,
                              hipStream_t stream) {
  const float* q  = (const float*)d_in[0];
  const float* k  = (const float*)d_in[1];
  const float* v  = (const float*)d_in[2];
  const float* Wq = (const float*)d_in[3];
  const float* bq = (const float*)d_in[4];
  const float* Wk = (const float*)d_in[5];
  const float* bk = (const float*)d_in[6];
  const float* Wv = (const float*)d_in[7];
  const float* bv = (const float*)d_in[8];
  float* out = (float*)d_out;

  // ws layout (bf16): qp 8MB | kp 8MB | vpT 2MB  (18MB total)
  short* qp  = (short*)d_ws;
  short* kpb = qp + (size_t)MTOT * DM;
  short* vpT = kpb + (size_t)MTOT * DM;

  proj_kernel<256, 256, false><<<MTOT / 64, 256, 0, stream>>>(q, Wq, bq, qp);
  proj_kernel<32, 256, false><<<MTOT / 64, 256, 0, stream>>>(k, Wk, bk, kpb);
  proj_kernel<256, 64, true><<<MTOT / 64, 256, 0, stream>>>(v, Wv, bv, vpT);
  attn_kernel<<<dim3(64, 4), 256, 0, stream>>>(qp, kpb, vpT, out);
}

// Round 5
// 364.093 us; speedup vs baseline: 1.0569x; 1.0569x over previous
//
#include <hip/hip_runtime.h>

// ---------------------------------------------------------------------------
// Fused attention: qp = q@Wq+bq ; kp = k@Wk+bk ; vp = v@Wv+bv
// S = qp kp^T / 16 ; A = softmax(S) ; A = where(threefry_mask, A/0.8, 0)
// out = A vp.   B=4, L=4096, D=256, DV=64.  fp32 in/out, bf16 MFMA internally.
//
// R2 (third resubmit after infra timeouts): Ksplit=4 across blocks
// (occupancy 11.7%->~50%), bf16-transposed W prep kernel for the
// projections, f32 partial O/Z + combine kernel.
// ---------------------------------------------------------------------------

typedef short s16x8 __attribute__((ext_vector_type(8)));   // 8 bf16 (4 VGPR)
typedef float f32x4 __attribute__((ext_vector_type(4)));

#define L    4096
#define DM   256
#define DV   64
#define MTOT 16384            // B*L rows
#define KSPLIT 4
#define KBLK 32               // keys per LDS tile

__device__ __forceinline__ short f2bf(float f) {           // RNE fp32->bf16
  unsigned u = __builtin_bit_cast(unsigned, f);
  u += 0x7FFFu + ((u >> 16) & 1u);
  return (short)(u >> 16);
}

__device__ __forceinline__ unsigned rotl32c(unsigned x, int r) {
  return (x << r) | (x >> (32 - r));                       // -> v_alignbit_b32
}

// JAX partitionable threefry2x32, key=(0,42), counter=(0,ctr).
// keep = uniform(bits0^bits1) < 0.8f  <=>  bits < 6710887*512  (verified R1)
// NOTE: the (x0,x1) pair serves ONE element (bits = x0^x1) in partitionable
// mode — there is no 2-elements-per-call shortcut.
__device__ __forceinline__ unsigned tf_keep(unsigned ctr) {
  unsigned x0 = 0u;
  unsigned x1 = ctr + 42u;                                 // + ks[1]
#define TFR(r) { x0 += x1; x1 = rotl32c(x1, r); x1 ^= x0; }
  TFR(13) TFR(15) TFR(26) TFR(6)
  x0 += 42u;          x1 += 0x1BD11BF1u;                   // ks2=0x1BD11BDA^42, +1
  TFR(17) TFR(29) TFR(16) TFR(24)
  x0 += 0x1BD11BF0u;  x1 += 2u;
  TFR(13) TFR(15) TFR(26) TFR(6)
  /* x0 += 0 */       x1 += 45u;                           // 42 + 3
  TFR(17) TFR(29) TFR(16) TFR(24)
  x0 += 42u;          x1 += 0x1BD11BF4u;                   // ks2 + 4
  TFR(13) TFR(15) TFR(26) TFR(6)
  x0 += 0x1BD11BF0u;  x1 += 5u;
#undef TFR
  return ((x0 ^ x1) < 3435974144u) ? 1u : 0u;
}

// ---------------------------------------------------------------------------
// Prep: W (f32, [K][N]) -> W^T (bf16, [N][K]) so proj B-fragments are
// contiguous s16x8 loads. Done once per launch; ~90K elements total.
// ---------------------------------------------------------------------------
__global__ __launch_bounds__(256) void prep_kernel(
    const float* __restrict__ Wq, const float* __restrict__ Wk,
    const float* __restrict__ Wv, short* __restrict__ wqT,
    short* __restrict__ wkT, short* __restrict__ wvT) {
  const int idx = blockIdx.x * 256 + threadIdx.x;
  if (idx < 65536) {                       // Wq 256x256 -> wqT[n*256+k]
    const int n = idx >> 8, k = idx & 255;
    wqT[idx] = f2bf(Wq[k * 256 + n]);
  }
  if (idx < 8192) {                        // Wk 32x256 -> wkT[n*32+k]
    const int n = idx >> 5, k = idx & 31;
    wkT[idx] = f2bf(Wk[k * 256 + n]);
  }
  if (idx < 16384) {                       // Wv 256x64 -> wvT[n*256+k]
    const int n = idx >> 8, k = idx & 255;
    wvT[idx] = f2bf(Wv[k * 64 + n]);
  }
}

// ---------------------------------------------------------------------------
// Projection: out[M,N](bf16) = A[M,K](f32) @ W[K,N] + bias, W^T given in bf16.
// Wave = 16 rows; block = 64 rows. TRANS_OUT stores out^T per-batch for V:
// vpT[(b*64+n)*4096 + key].
// MFMA 16x16x32 bf16 frags: A/B: lane (l&15)=m/n, k=(l>>4)*8+j ;
// C: row=(l>>4)*4+j, col=l&15.
// ---------------------------------------------------------------------------
template <int K, int N, bool TRANS_OUT>
__global__ __launch_bounds__(256) void proj_kernel(
    const float* __restrict__ A, const short* __restrict__ WT,
    const float* __restrict__ bias, short* __restrict__ out) {
  const int lane = threadIdx.x & 63;
  const int wv   = threadIdx.x >> 6;
  const int l15 = lane & 15, l4 = lane >> 4;
  const int rowbase = blockIdx.x * 64 + wv * 16;
  constexpr int NT = N / 16;
  constexpr int KC = K / 32;
  f32x4 acc[NT];
#pragma unroll
  for (int i = 0; i < NT; ++i) acc[i] = (f32x4){0.f, 0.f, 0.f, 0.f};
  const int arow = rowbase + l15;
#pragma unroll
  for (int kc = 0; kc < KC; ++kc) {
    const f32x4* ap = (const f32x4*)(A + (size_t)arow * K + kc * 32 + l4 * 8);
    f32x4 a0 = ap[0], a1 = ap[1];
    s16x8 af;
#pragma unroll
    for (int j = 0; j < 4; ++j) { af[j] = f2bf(a0[j]); af[4 + j] = f2bf(a1[j]); }
#pragma unroll
    for (int nt = 0; nt < NT; ++nt) {
      const s16x8 bf = *(const s16x8*)(WT + (size_t)(nt * 16 + l15) * K + kc * 32 + l4 * 8);
      acc[nt] = __builtin_amdgcn_mfma_f32_16x16x32_bf16(af, bf, acc[nt], 0, 0, 0);
    }
  }
#pragma unroll
  for (int nt = 0; nt < NT; ++nt) {
    const int gcol = nt * 16 + l15;
    const float bv = bias[gcol];
#pragma unroll
    for (int j = 0; j < 4; ++j) {
      const int grow = rowbase + l4 * 4 + j;
      const float vv = acc[nt][j] + bv;
      if (TRANS_OUT) {
        const int b = grow >> 12, key = grow & 4095;
        out[(size_t)(b * 64 + gcol) * L + key] = f2bf(vv);
      } else {
        out[(size_t)grow * N + gcol] = f2bf(vv);
      }
    }
  }
}

// ---------------------------------------------------------------------------
// Fused flash attention + exact-threefry dropout, split-K.
// Block: 256 thr (4 waves), 64 q-rows (16/wave), K-range = 1024 keys (z).
// kbuf [32][256] bf16 swizzled ^(row&7)<<3 ; vbuf V^T [64dv][32k] ^(row&3)<<3 ;
// pbuf per-wave [16][32] ^(row&3)<<3 for the C-frag -> A-frag transpose of P.
// Emits unnormalized partial O (f32) and partial Z per row.
// ---------------------------------------------------------------------------
__global__ __launch_bounds__(256, 4) void attn_kernel(
    const short* __restrict__ qp, const short* __restrict__ kp,
    const short* __restrict__ vpT, float* __restrict__ partO,
    float* __restrict__ partZ) {
  __shared__ __align__(16) short kbuf[KBLK * 256];   // 16 KB
  __shared__ __align__(16) short vbuf[64 * KBLK];    // 4 KB
  __shared__ __align__(16) short pbuf[4][16 * KBLK]; // 4 KB
  const int tid = threadIdx.x;
  const int lane = tid & 63, wv = tid >> 6;
  const int l15 = lane & 15, l4 = lane >> 4;
  const int qt = blockIdx.x, b = blockIdx.y, z = blockIdx.z;
  const int qrow0 = b * L + qt * 64 + wv * 16;  // global row in [MTOT] space

  // Q fragments held in registers (8 k-chunks of 32)
  s16x8 qf[8];
#pragma unroll
  for (int kc = 0; kc < 8; ++kc)
    qf[kc] = *(const s16x8*)(qp + (size_t)(qrow0 + l15) * DM + kc * 32 + l4 * 8);

  f32x4 accO[4];
#pragma unroll
  for (int i = 0; i < 4; ++i) accO[i] = (f32x4){0.f, 0.f, 0.f, 0.f};
  float zpart[4] = {0.f, 0.f, 0.f, 0.f};

  const unsigned qglob = (unsigned)qrow0;
  constexpr float CEXP = 0.09016844005556021f;  // log2(e)/16
  const int kb0 = z * (L / KSPLIT / KBLK);      // 32 tiles of 32 keys

  for (int i = 0; i < L / KSPLIT / KBLK; ++i) {
    const int kbase = (kb0 + i) * KBLK;         // global key offset
    __syncthreads();
    {  // stage K tile: 32 rows x 512B, swizzle byte ^= (row&7)*16
      const short* src = kp + (size_t)(b * L + kbase) * DM;
#pragma unroll
      for (int it = 0; it < 4; ++it) {
        const int c = it * 256 + tid;
        const int row = c >> 5, off = (c & 31) * 8;
        const int e = (row * 256 + off) ^ ((row & 7) << 3);
        *(s16x8*)(kbuf + e) = *(const s16x8*)(src + (size_t)row * DM + off);
      }
      // stage V^T tile: 64 dv-rows x 64B
      const short* vsrc = vpT + (size_t)b * 64 * L + kbase;
      const int row = tid >> 2, off = (tid & 3) * 8;
      const int e = (row * KBLK + off) ^ ((row & 3) << 3);
      *(s16x8*)(vbuf + e) = *(const s16x8*)(vsrc + (size_t)row * L + off);
    }
    __syncthreads();

    // ---- QK^T: 2 key-tiles x 8 k-chunks ----
    f32x4 sf[2];
#pragma unroll
    for (int kt = 0; kt < 2; ++kt) sf[kt] = (f32x4){0.f, 0.f, 0.f, 0.f};
#pragma unroll
    for (int kc = 0; kc < 8; ++kc) {
#pragma unroll
      for (int kt = 0; kt < 2; ++kt) {
        const int row = kt * 16 + l15;
        const int e = (row * 256 + kc * 32 + l4 * 8) ^ ((row & 7) << 3);
        const s16x8 kf = *(const s16x8*)(kbuf + e);
        sf[kt] = __builtin_amdgcn_mfma_f32_16x16x32_bf16(qf[kc], kf, sf[kt], 0, 0, 0);
      }
    }

    // ---- dropout masks: 8 independent threefry chains (ILP) ----
    unsigned keep = 0;
#pragma unroll
    for (int kt = 0; kt < 2; ++kt) {
#pragma unroll
      for (int j = 0; j < 4; ++j) {
        const unsigned q = qglob + (unsigned)(l4 * 4 + j);
        const unsigned idx = (q << 12) + (unsigned)(kbase + kt * 16 + l15);
        keep |= tf_keep(idx) << (kt * 4 + j);
      }
    }

    // ---- exp, Z accumulation, store masked P (bf16) into pbuf ----
#pragma unroll
    for (int kt = 0; kt < 2; ++kt) {
#pragma unroll
      for (int j = 0; j < 4; ++j) {
        const float e = exp2f(sf[kt][j] * CEXP);
        zpart[j] += e;
        const float pd = ((keep >> (kt * 4 + j)) & 1u) ? e : 0.0f;
        const int row = l4 * 4 + j, col = kt * 16 + l15;
        const int pe = (row * KBLK + col) ^ ((row & 3) << 3);
        pbuf[wv][pe] = f2bf(pd);
      }
    }
    // pbuf is per-wave: ds_writes above and reads below are same-wave,
    // ordered via lgkmcnt. The barrier below protects kbuf/vbuf reuse.
    __syncthreads();

    // ---- PV: P[16x32] @ V[32x64] (one K=32 MFMA chunk) ----
    {
      const int pe = (l15 * KBLK + l4 * 8) ^ ((l15 & 3) << 3);
      const s16x8 pa = *(const s16x8*)(&pbuf[wv][0] + pe);
#pragma unroll
      for (int nt = 0; nt < 4; ++nt) {
        const int vrow = nt * 16 + l15;
        const int ve = (vrow * KBLK + l4 * 8) ^ ((vrow & 3) << 3);
        const s16x8 vb = *(const s16x8*)(vbuf + ve);
        accO[nt] = __builtin_amdgcn_mfma_f32_16x16x32_bf16(pa, vb, accO[nt], 0, 0, 0);
      }
    }
  }

  // ---- epilogue: reduce Z across the 16-lane group, store partials ----
#pragma unroll
  for (int j = 0; j < 4; ++j) {
    float zf = zpart[j];
    zf += __shfl_xor(zf, 1);
    zf += __shfl_xor(zf, 2);
    zf += __shfl_xor(zf, 4);
    zf += __shfl_xor(zf, 8);
    const int grow = qrow0 + l4 * 4 + j;
    if (l15 == 0) partZ[(size_t)z * MTOT + grow] = zf;
#pragma unroll
    for (int nt = 0; nt < 4; ++nt)
      partO[((size_t)z * MTOT + grow) * DV + nt * 16 + l15] = accO[nt][j];
  }
}

// ---------------------------------------------------------------------------
// Combine: out[row][dv] = sum_z O / (0.8 * sum_z Z[row]).  4 f32 per thread.
// ---------------------------------------------------------------------------
__global__ __launch_bounds__(256) void combine_kernel(
    const float* __restrict__ partO, const float* __restrict__ partZ,
    float* __restrict__ out) {
  const int i = blockIdx.x * 256 + threadIdx.x;  // i indexes groups of 4 f32
  const int row = i >> 4;
  f32x4 acc = (f32x4){0.f, 0.f, 0.f, 0.f};
  float zf = 0.f;
#pragma unroll
  for (int zz = 0; zz < KSPLIT; ++zz) {
    acc += *(const f32x4*)(partO + (size_t)zz * MTOT * DV + (size_t)i * 4);
    zf += partZ[(size_t)zz * MTOT + row];
  }
  const float inv = 1.0f / (0.8f * zf);
  f32x4 r = acc * inv;
  *(f32x4*)(out + (size_t)i * 4) = r;
}

// ---------------------------------------------------------------------------
extern "C" void kernel_launch(void* const* d_in, const int* in_sizes, int n_in,
                              void* d_out, int out_size, void* d_ws, size_t ws_size,
                              hipStream_t stream) {
  const float* q  = (const float*)d_in[0];
  const float* k  = (const float*)d_in[1];
  const float* v  = (const float*)d_in[2];
  const float* Wq = (const float*)d_in[3];
  const float* bq = (const float*)d_in[4];
  const float* Wk = (const float*)d_in[5];
  const float* bk = (const float*)d_in[6];
  const float* Wv = (const float*)d_in[7];
  const float* bv = (const float*)d_in[8];
  float* out = (float*)d_out;

  // ws layout: qp 8MB | kp 8MB | vpT 2MB | partO 16MB | partZ 256KB | WT bufs
  short* qp  = (short*)d_ws;
  short* kpb = qp + (size_t)MTOT * DM;
  short* vpT = kpb + (size_t)MTOT * DM;
  float* partO = (float*)(vpT + (size_t)4 * 64 * L);
  float* partZ = partO + (size_t)KSPLIT * MTOT * DV;
  short* wqT = (short*)(partZ + (size_t)KSPLIT * MTOT);
  short* wkT = wqT + 256 * 256;
  short* wvT = wkT + 32 * 256;

  prep_kernel<<<352, 256, 0, stream>>>(Wq, Wk, Wv, wqT, wkT, wvT);
  proj_kernel<256, 256, false><<<MTOT / 64, 256, 0, stream>>>(q, wqT, bq, qp);
  proj_kernel<32, 256, false><<<MTOT / 64, 256, 0, stream>>>(k, wkT, bk, kpb);
  proj_kernel<256, 64, true><<<MTOT / 64, 256, 0, stream>>>(v, wvT, bv, vpT);
  attn_kernel<<<dim3(64, 4, KSPLIT), 256, 0, stream>>>(qp, kpb, vpT, partO, partZ);
  combine_kernel<<<MTOT * DV / 1024, 256, 0, stream>>>(partO, partZ, out);
}